// Round 1
// baseline (828.945 us; speedup 1.0000x reference)
//
#include <hip/hip_runtime.h>
#include <hip/hip_bf16.h>
#include <math.h>

#define BB 8
#define CC 384
#define NT 1024      // tokens = 32*32
#define NHEAD 8
#define HD 48
#define HIDDEN 192
#define THREEC 1152

// ---------------- bias table: [63*63][8] ----------------
__global__ __launch_bounds__(256) void k_bias_table(
    const float* __restrict__ w1, const float* __restrict__ b1,
    const float* __restrict__ w2, const float* __restrict__ b2,
    float* __restrict__ tab) {
  int p = blockIdx.x * blockDim.x + threadIdx.x;
  if (p >= 63 * 63) return;
  float rh = (float)(p / 63 - 31) * (1.0f / 31.0f);
  float rw = (float)(p % 63 - 31) * (1.0f / 31.0f);
  float acc[8];
#pragma unroll
  for (int h = 0; h < 8; h++) acc[h] = b2[h];
  for (int j = 0; j < HIDDEN; j++) {
    float pre = fmaf(rh, w1[j], fmaf(rw, w1[HIDDEN + j], b1[j]));
    float g = 0.5f * pre * (1.0f + erff(pre * 0.70710678118654752f));
#pragma unroll
    for (int h = 0; h < 8; h++) acc[h] = fmaf(g, w2[j * 8 + h], acc[h]);
  }
#pragma unroll
  for (int h = 0; h < 8; h++) tab[p * 8 + h] = acc[h];
}

// ---------------- QKV GEMM: tokens[8192,384] @ w[384,1152] ----------------
// writes Q (pre-scaled), K, V in [B, NHEAD, NT, HD] layout
__global__ __launch_bounds__(256) void k_qkv(
    const float* __restrict__ x, const float* __restrict__ w,
    const float* __restrict__ bias,
    float* __restrict__ Q, float* __restrict__ Kb, float* __restrict__ Vb) {
  __shared__ float As[16][68];
  __shared__ float Bs[16][68];
  const int c0 = blockIdx.x * 64;
  const int m0 = blockIdx.y * 64;
  const int b = m0 >> 10;
  const int n0 = m0 & 1023;
  const int tid = threadIdx.x;
  const int ty = tid / 16, tx = tid % 16;
  float acc[4][4] = {};
  for (int k0 = 0; k0 < CC; k0 += 16) {
#pragma unroll
    for (int e = 0; e < 4; e++) {
      int i = tid + e * 256;
      int kl = i >> 6, ml = i & 63;
      As[kl][ml] = x[(size_t)b * CC * NT + (size_t)(k0 + kl) * NT + n0 + ml];
      Bs[kl][ml] = w[(size_t)(k0 + kl) * THREEC + c0 + ml];
    }
    __syncthreads();
#pragma unroll
    for (int k = 0; k < 16; k++) {
      float4 a = *(const float4*)&As[k][ty * 4];
      float4 bv = *(const float4*)&Bs[k][tx * 4];
      float av[4] = {a.x, a.y, a.z, a.w};
      float bvv[4] = {bv.x, bv.y, bv.z, bv.w};
#pragma unroll
      for (int i = 0; i < 4; i++)
#pragma unroll
        for (int j = 0; j < 4; j++) acc[i][j] = fmaf(av[i], bvv[j], acc[i][j]);
    }
    __syncthreads();
  }
  const float scale = 0.14433756729740643f;  // 48^-0.5
#pragma unroll
  for (int i = 0; i < 4; i++) {
    int n = n0 + ty * 4 + i;
#pragma unroll
    for (int j = 0; j < 4; j++) {
      int cg = c0 + tx * 4 + j;
      float v = acc[i][j] + bias[cg];
      int which = cg / 384;
      int r = cg - which * 384;
      int head = r / 48;
      int d = r - head * 48;
      size_t off = ((size_t)(b * NHEAD + head) * NT + n) * HD + d;
      if (which == 0) Q[off] = v * scale;
      else if (which == 1) Kb[off] = v;
      else Vb[off] = v;
    }
  }
}

// ---------------- S = Q @ K^T + bias, per bh ----------------
__global__ __launch_bounds__(256) void k_qk(
    const float* __restrict__ Q, const float* __restrict__ Kb,
    const float* __restrict__ tab, float* __restrict__ S, int bh0) {
  __shared__ float Qs[48][68];
  __shared__ float Ks[48][68];
  const int bh = bh0 + blockIdx.z;
  const int h = bh & 7;
  const int m0 = blockIdx.x * 64;
  const int n0 = blockIdx.y * 64;
  const int tid = threadIdx.x;
  const int ty = tid / 16, tx = tid % 16;
  const float* qb = Q + (size_t)bh * NT * HD;
  const float* kb = Kb + (size_t)bh * NT * HD;
#pragma unroll
  for (int e = 0; e < 12; e++) {
    int i = tid + e * 256;
    int nl = i / 48, d = i - nl * 48;
    Qs[d][nl] = qb[(size_t)(n0 + nl) * HD + d];
    Ks[d][nl] = kb[(size_t)(m0 + nl) * HD + d];
  }
  __syncthreads();
  float acc[4][4] = {};
#pragma unroll 8
  for (int d = 0; d < 48; d++) {
    float4 a = *(const float4*)&Qs[d][ty * 4];
    float4 bv = *(const float4*)&Ks[d][tx * 4];
    float av[4] = {a.x, a.y, a.z, a.w};
    float bvv[4] = {bv.x, bv.y, bv.z, bv.w};
#pragma unroll
    for (int i = 0; i < 4; i++)
#pragma unroll
      for (int j = 0; j < 4; j++) acc[i][j] = fmaf(av[i], bvv[j], acc[i][j]);
  }
  float* sb = S + (size_t)(bh - bh0) * NT * NT;
#pragma unroll
  for (int i = 0; i < 4; i++) {
    int n = n0 + ty * 4 + i;
    int in_ = n >> 5, jn = n & 31;
#pragma unroll
    for (int j = 0; j < 4; j++) {
      int m = m0 + tx * 4 + j;
      int dh = in_ - (m >> 5) + 31;
      int dw = jn - (m & 31) + 31;
      sb[(size_t)n * NT + m] = acc[i][j] + tab[(dh * 63 + dw) * 8 + h];
    }
  }
}

// ---------------- softmax over rows of 1024 ----------------
__global__ __launch_bounds__(256) void k_softmax(float* __restrict__ S) {
  const int r = blockIdx.x;
  const int tid = threadIdx.x;
  float4* row = (float4*)(S + (size_t)r * NT);
  float4 v = row[tid];
  float mx = fmaxf(fmaxf(v.x, v.y), fmaxf(v.z, v.w));
#pragma unroll
  for (int o = 32; o; o >>= 1) mx = fmaxf(mx, __shfl_xor(mx, o));
  __shared__ float red[4], red2[4];
  if ((tid & 63) == 0) red[tid >> 6] = mx;
  __syncthreads();
  mx = fmaxf(fmaxf(red[0], red[1]), fmaxf(red[2], red[3]));
  v.x = __expf(v.x - mx);
  v.y = __expf(v.y - mx);
  v.z = __expf(v.z - mx);
  v.w = __expf(v.w - mx);
  float s = v.x + v.y + v.z + v.w;
#pragma unroll
  for (int o = 32; o; o >>= 1) s += __shfl_xor(s, o);
  if ((tid & 63) == 0) red2[tid >> 6] = s;
  __syncthreads();
  s = red2[0] + red2[1] + red2[2] + red2[3];
  float inv = 1.0f / s;
  v.x *= inv; v.y *= inv; v.z *= inv; v.w *= inv;
  row[tid] = v;
}

// ---------------- out_tokens = P @ V,  [B, NT, C] layout ----------------
__global__ __launch_bounds__(256) void k_pv(
    const float* __restrict__ S, const float* __restrict__ Vb,
    float* __restrict__ AT, int bh0) {
  __shared__ float Pt[64][68];
  __shared__ float Vs[64][49];
  const int bh = bh0 + blockIdx.y;
  const int b = bh >> 3, h = bh & 7;
  const int n0 = blockIdx.x * 64;
  const int tid = threadIdx.x;
  const int ty = tid / 16, tx = tid % 16;
  const float* P = S + (size_t)(bh - bh0) * NT * NT;
  const float* vb = Vb + (size_t)bh * NT * HD;
  float acc[4][3] = {};
  for (int m0 = 0; m0 < NT; m0 += 64) {
#pragma unroll
    for (int e = 0; e < 16; e++) {
      int i = tid + e * 256;
      int ml = i & 63, nl = i >> 6;
      Pt[ml][nl] = P[(size_t)(n0 + nl) * NT + m0 + ml];
    }
#pragma unroll
    for (int e = 0; e < 12; e++) {
      int i = tid + e * 256;
      int ml = i / 48, d = i - ml * 48;
      Vs[ml][d] = vb[(size_t)(m0 + ml) * HD + d];
    }
    __syncthreads();
#pragma unroll 16
    for (int m = 0; m < 64; m++) {
      float4 p4 = *(const float4*)&Pt[m][ty * 4];
      float pv[4] = {p4.x, p4.y, p4.z, p4.w};
      float v0 = Vs[m][tx * 3], v1 = Vs[m][tx * 3 + 1], v2 = Vs[m][tx * 3 + 2];
#pragma unroll
      for (int i = 0; i < 4; i++) {
        acc[i][0] = fmaf(pv[i], v0, acc[i][0]);
        acc[i][1] = fmaf(pv[i], v1, acc[i][1]);
        acc[i][2] = fmaf(pv[i], v2, acc[i][2]);
      }
    }
    __syncthreads();
  }
#pragma unroll
  for (int i = 0; i < 4; i++)
#pragma unroll
    for (int j = 0; j < 3; j++)
      AT[((size_t)b * NT + n0 + ty * 4 + i) * CC + h * HD + tx * 3 + j] = acc[i][j];
}

// ---------------- out[b][c][n] = AT[b][n][:] @ proj_w + proj_b ----------------
__global__ __launch_bounds__(256) void k_proj(
    const float* __restrict__ AT, const float* __restrict__ W,
    const float* __restrict__ bias, float* __restrict__ out) {
  __shared__ float Ws[16][68];
  __shared__ float As[16][68];
  const int c0 = blockIdx.x * 64;
  const int n0 = blockIdx.y * 64;
  const int b = blockIdx.z;
  const int tid = threadIdx.x;
  const int ty = tid / 16, tx = tid % 16;
  float acc[4][4] = {};
  for (int k0 = 0; k0 < CC; k0 += 16) {
#pragma unroll
    for (int e = 0; e < 4; e++) {
      int i = tid + e * 256;
      int kl = i >> 6, cl = i & 63;
      Ws[kl][cl] = W[(size_t)(k0 + kl) * CC + c0 + cl];
      int kl2 = i & 15, nl = i >> 4;
      As[kl2][nl] = AT[((size_t)b * NT + n0 + nl) * CC + k0 + kl2];
    }
    __syncthreads();
#pragma unroll
    for (int k = 0; k < 16; k++) {
      float4 wv = *(const float4*)&Ws[k][ty * 4];
      float4 av = *(const float4*)&As[k][tx * 4];
      float wvv[4] = {wv.x, wv.y, wv.z, wv.w};
      float avv[4] = {av.x, av.y, av.z, av.w};
#pragma unroll
      for (int i = 0; i < 4; i++)
#pragma unroll
        for (int j = 0; j < 4; j++) acc[i][j] = fmaf(wvv[i], avv[j], acc[i][j]);
    }
    __syncthreads();
  }
#pragma unroll
  for (int i = 0; i < 4; i++) {
    int c = c0 + ty * 4 + i;
    float bc = bias[c];
#pragma unroll
    for (int j = 0; j < 4; j++)
      out[((size_t)b * CC + c) * NT + n0 + tx * 4 + j] = acc[i][j] + bc;
  }
}

extern "C" void kernel_launch(void* const* d_in, const int* in_sizes, int n_in,
                              void* d_out, int out_size, void* d_ws, size_t ws_size,
                              hipStream_t stream) {
  const float* x = (const float*)d_in[0];
  const float* qkv_w = (const float*)d_in[1];
  const float* qkv_b = (const float*)d_in[2];
  const float* proj_w = (const float*)d_in[3];
  const float* proj_b = (const float*)d_in[4];
  const float* w1 = (const float*)d_in[5];
  const float* b1 = (const float*)d_in[6];
  const float* w2 = (const float*)d_in[7];
  const float* b2 = (const float*)d_in[8];
  float* out = (float*)d_out;

  float* ws = (float*)d_ws;
  const size_t QKV_SZ = (size_t)BB * NHEAD * NT * HD;  // 3,145,728 floats
  float* Q = ws;
  float* Kb = Q + QKV_SZ;
  float* Vb = Kb + QKV_SZ;
  float* AT = Vb + QKV_SZ;           // [B, NT, C] — also 3,145,728 floats
  float* tab = AT + QKV_SZ;
  float* S = tab + 32768;            // bias table padded to 32768 floats

  size_t used = (size_t)(S - ws);
  size_t avail = ws_size / 4 > used ? ws_size / 4 - used : 0;
  int chunk = 64;
  while (chunk > 1 && (size_t)chunk * NT * NT > avail) chunk >>= 1;

  k_bias_table<<<dim3(16), dim3(256), 0, stream>>>(w1, b1, w2, b2, tab);
  k_qkv<<<dim3(18, 128), dim3(256), 0, stream>>>(x, qkv_w, qkv_b, Q, Kb, Vb);
  for (int bh0 = 0; bh0 < BB * NHEAD; bh0 += chunk) {
    k_qk<<<dim3(16, 16, chunk), dim3(256), 0, stream>>>(Q, Kb, tab, S, bh0);
    k_softmax<<<dim3(chunk * NT), dim3(256), 0, stream>>>(S);
    k_pv<<<dim3(16, chunk), dim3(256), 0, stream>>>(S, Vb, AT, bh0);
  }
  k_proj<<<dim3(6, 16, BB), dim3(256), 0, stream>>>(AT, proj_w, proj_b, out);
}

// Round 2
// 256.244 us; speedup vs baseline: 3.2350x; 3.2350x over previous
//
#include <hip/hip_runtime.h>
#include <hip/hip_bf16.h>
#include <math.h>

#define BB 8
#define CC 384
#define NT 1024
#define NHEAD 8
#define HD 48
#define HIDDEN 192
#define THREEC 1152

typedef short short8 __attribute__((ext_vector_type(8)));
typedef float f32x4 __attribute__((ext_vector_type(4)));

// ---------------- bias table: [8][63*63] (head-major for coalesced reload) ----------------
__global__ __launch_bounds__(256) void k_bias_table(
    const float* __restrict__ w1, const float* __restrict__ b1,
    const float* __restrict__ w2, const float* __restrict__ b2,
    float* __restrict__ tab) {
  int p = blockIdx.x * blockDim.x + threadIdx.x;
  if (p >= 63 * 63) return;
  float rh = (float)(p / 63 - 31) * (1.0f / 31.0f);
  float rw = (float)(p % 63 - 31) * (1.0f / 31.0f);
  float acc[8];
#pragma unroll
  for (int h = 0; h < 8; h++) acc[h] = b2[h];
  for (int j = 0; j < HIDDEN; j++) {
    float pre = fmaf(rh, w1[j], fmaf(rw, w1[HIDDEN + j], b1[j]));
    float g = 0.5f * pre * (1.0f + erff(pre * 0.70710678118654752f));
#pragma unroll
    for (int h = 0; h < 8; h++) acc[h] = fmaf(g, w2[j * 8 + h], acc[h]);
  }
#pragma unroll
  for (int h = 0; h < 8; h++) tab[h * 3969 + p] = acc[h];
}

// ---------------- transpose + fp32->bf16: src[z][R][C] -> dst[z][C][R] ----------------
__global__ __launch_bounds__(256) void k_tcvt(const float* __restrict__ src,
                                              __hip_bfloat16* __restrict__ dst,
                                              int R, int C) {
  __shared__ float t[32][33];
  src += (size_t)blockIdx.z * R * C;
  dst += (size_t)blockIdx.z * R * C;
  const int c0 = blockIdx.x * 32, r0 = blockIdx.y * 32;
  const int tid = threadIdx.x;
#pragma unroll
  for (int e = 0; e < 4; e++) {
    int i = tid + e * 256;
    int r = i >> 5, c = i & 31;
    t[r][c] = src[(size_t)(r0 + r) * C + c0 + c];
  }
  __syncthreads();
#pragma unroll
  for (int e = 0; e < 4; e++) {
    int i = tid + e * 256;
    int c = i >> 5, r = i & 31;
    dst[(size_t)(c0 + c) * R + r0 + r] = __float2bfloat16(t[r][c]);
  }
}

// ---------------- QKV GEMM (bf16 MFMA): xt[8192,384] @ wtq^T -> Q/K (d-pad 64), Vt ----------------
__global__ __launch_bounds__(256) void k_qkv_mfma(
    const __hip_bfloat16* __restrict__ xt,   // [8192][384]
    const __hip_bfloat16* __restrict__ wtq,  // [1152][384]
    const float* __restrict__ qkv_b,
    __hip_bfloat16* __restrict__ Qb,  // [64][1024][64]
    __hip_bfloat16* __restrict__ Kb,  // [64][1024][64]
    __hip_bfloat16* __restrict__ Vt)  // [64][48][1024]
{
  __shared__ __align__(16) short As[64 * 72];
  __shared__ __align__(16) short Bs[64 * 72];
  const int m0 = blockIdx.x * 64;  // token tile
  const int n0 = blockIdx.y * 64;  // out-channel tile
  const int tid = threadIdx.x;
  const int wv = tid >> 6, lane = tid & 63, quad = lane >> 4, lq = lane & 15;
  f32x4 acc[4];
#pragma unroll
  for (int nt = 0; nt < 4; nt++) acc[nt] = (f32x4){0.f, 0.f, 0.f, 0.f};
  for (int kk = 0; kk < CC; kk += 64) {
#pragma unroll
    for (int e = 0; e < 2; e++) {
      int cid = tid + e * 256;
      int row = cid >> 3, g = cid & 7;
      *(short8*)(As + row * 72 + g * 8) =
          *(const short8*)((const short*)xt + (size_t)(m0 + row) * 384 + kk + g * 8);
      *(short8*)(Bs + row * 72 + g * 8) =
          *(const short8*)((const short*)wtq + (size_t)(n0 + row) * 384 + kk + g * 8);
    }
    __syncthreads();
    short8 a0 = *(const short8*)(As + (wv * 16 + lq) * 72 + quad * 8);
    short8 a1 = *(const short8*)(As + (wv * 16 + lq) * 72 + 32 + quad * 8);
#pragma unroll
    for (int nt = 0; nt < 4; nt++) {
      acc[nt] = __builtin_amdgcn_mfma_f32_16x16x32_bf16(
          a0, *(const short8*)(Bs + (nt * 16 + lq) * 72 + quad * 8), acc[nt], 0, 0, 0);
      acc[nt] = __builtin_amdgcn_mfma_f32_16x16x32_bf16(
          a1, *(const short8*)(Bs + (nt * 16 + lq) * 72 + 32 + quad * 8), acc[nt], 0, 0, 0);
    }
    __syncthreads();
  }
  const float scale = 0.14433756729740643f;  // 48^-0.5
#pragma unroll
  for (int nt = 0; nt < 4; nt++) {
    int cg = n0 + nt * 16 + lq;
    float bias = qkv_b[cg];
    int which = cg >= 768 ? 2 : (cg >= 384 ? 1 : 0);
    int rr = cg - which * 384;
    int head = rr / 48, d = rr - head * 48;
#pragma unroll
    for (int r = 0; r < 4; r++) {
      int token = m0 + wv * 16 + quad * 4 + r;
      int b = token >> 10, n = token & 1023;
      int bh = b * 8 + head;
      float v = acc[nt][r] + bias;
      if (which == 0)
        Qb[((size_t)(bh << 10) + n) * 64 + d] = __float2bfloat16(v * scale);
      else if (which == 1)
        Kb[((size_t)(bh << 10) + n) * 64 + d] = __float2bfloat16(v);
      else
        Vt[((size_t)bh * 48 + d) * 1024 + n] = __float2bfloat16(v);
    }
  }
}

// ---------------- fused flash attention: per (q-tile 64, bh) ----------------
__global__ __launch_bounds__(256) void k_flash(
    const __hip_bfloat16* __restrict__ Qb, const __hip_bfloat16* __restrict__ Kb,
    const __hip_bfloat16* __restrict__ Vt, const float* __restrict__ tab,
    __hip_bfloat16* __restrict__ ATb)  // [8][1024][384]
{
  __shared__ __align__(16) float tabh_l[63 * 64];
  __shared__ __align__(16) short Ks_l[64 * 72];
  __shared__ __align__(16) short Vt_l[48 * 72];
  __shared__ __align__(16) short Ps_l[4 * 16 * 72];
  const int tid = threadIdx.x;
  const int wv = tid >> 6, lane = tid & 63, quad = lane >> 4, lq = lane & 15;
  const int q0 = blockIdx.x * 64;
  const int bh = blockIdx.y;
  const int b = bh >> 3, h = bh & 7;

  for (int i = tid; i < 3969; i += 256)
    tabh_l[(i / 63) * 64 + (i % 63)] = tab[h * 3969 + i];

  short8 qf[2];
  {
    const size_t qrow = ((size_t)(bh << 10) + q0 + wv * 16 + lq) * 64;
    qf[0] = *(const short8*)((const short*)Qb + qrow + quad * 8);
    qf[1] = *(const short8*)((const short*)Qb + qrow + 32 + quad * 8);
  }
  f32x4 O[3];
#pragma unroll
  for (int dt = 0; dt < 3; dt++) O[dt] = (f32x4){0.f, 0.f, 0.f, 0.f};
  float M[4], L[4];
  int inr[4], jnr[4], nrow[4];
#pragma unroll
  for (int r = 0; r < 4; r++) {
    M[r] = -1e30f;
    L[r] = 0.f;
    nrow[r] = q0 + wv * 16 + quad * 4 + r;
    inr[r] = nrow[r] >> 5;
    jnr[r] = nrow[r] & 31;
  }
  __syncthreads();

  for (int m0 = 0; m0 < NT; m0 += 64) {
    {
      int cid = tid, row = cid >> 3, g = cid & 7;
      *(short8*)(Ks_l + row * 72 + g * 8) =
          *(const short8*)((const short*)Kb + ((size_t)(bh << 10) + m0 + row) * 64 + g * 8);
      cid = tid + 256; row = cid >> 3; g = cid & 7;
      *(short8*)(Ks_l + row * 72 + g * 8) =
          *(const short8*)((const short*)Kb + ((size_t)(bh << 10) + m0 + row) * 64 + g * 8);
      for (int c2 = tid; c2 < 384; c2 += 256) {
        int rowv = c2 >> 3, gv = c2 & 7;
        *(short8*)(Vt_l + rowv * 72 + gv * 8) =
            *(const short8*)((const short*)Vt + ((size_t)bh * 48 + rowv) * 1024 + m0 + gv * 8);
      }
    }
    __syncthreads();
    // S = Q K^T + bias
    float s[4][4];
#pragma unroll
    for (int nt = 0; nt < 4; nt++) {
      f32x4 c = (f32x4){0.f, 0.f, 0.f, 0.f};
      c = __builtin_amdgcn_mfma_f32_16x16x32_bf16(
          qf[0], *(const short8*)(Ks_l + (nt * 16 + lq) * 72 + quad * 8), c, 0, 0, 0);
      c = __builtin_amdgcn_mfma_f32_16x16x32_bf16(
          qf[1], *(const short8*)(Ks_l + (nt * 16 + lq) * 72 + 32 + quad * 8), c, 0, 0, 0);
      int mg = m0 + nt * 16 + lq;
      int im = mg >> 5, jm = mg & 31;
#pragma unroll
      for (int r = 0; r < 4; r++)
        s[nt][r] = c[r] + tabh_l[(inr[r] - im + 31) * 64 + (jnr[r] - jm + 31)];
    }
    // online softmax (rows split across the 16 lanes of each quad-group)
    float tmax[4], tsum[4], p[4][4];
#pragma unroll
    for (int r = 0; r < 4; r++) {
      tmax[r] = fmaxf(fmaxf(s[0][r], s[1][r]), fmaxf(s[2][r], s[3][r]));
#pragma unroll
      for (int msk = 1; msk <= 8; msk <<= 1) tmax[r] = fmaxf(tmax[r], __shfl_xor(tmax[r], msk));
      float newM = fmaxf(M[r], tmax[r]);
      float alpha = __expf(M[r] - newM);
      M[r] = newM;
#pragma unroll
      for (int nt = 0; nt < 4; nt++) p[nt][r] = __expf(s[nt][r] - newM);
      tsum[r] = p[0][r] + p[1][r] + p[2][r] + p[3][r];
#pragma unroll
      for (int msk = 1; msk <= 8; msk <<= 1) tsum[r] += __shfl_xor(tsum[r], msk);
      L[r] = L[r] * alpha + tsum[r];
#pragma unroll
      for (int dt = 0; dt < 3; dt++) O[dt][r] *= alpha;
    }
    // P -> LDS (C-layout -> A-layout round trip)
#pragma unroll
    for (int nt = 0; nt < 4; nt++)
#pragma unroll
      for (int r = 0; r < 4; r++)
        ((__hip_bfloat16*)Ps_l)[wv * 1152 + (quad * 4 + r) * 72 + nt * 16 + lq] =
            __float2bfloat16(p[nt][r]);
    __syncthreads();
    // O += P V
#pragma unroll
    for (int ks = 0; ks < 2; ks++) {
      short8 af = *(const short8*)(Ps_l + wv * 1152 + lq * 72 + ks * 32 + quad * 8);
#pragma unroll
      for (int dt = 0; dt < 3; dt++)
        O[dt] = __builtin_amdgcn_mfma_f32_16x16x32_bf16(
            af, *(const short8*)(Vt_l + (dt * 16 + lq) * 72 + ks * 32 + quad * 8), O[dt], 0, 0, 0);
    }
    __syncthreads();
  }
#pragma unroll
  for (int r = 0; r < 4; r++) {
    float inv = 1.0f / L[r];
#pragma unroll
    for (int dt = 0; dt < 3; dt++)
      ATb[((size_t)(b << 10) + nrow[r]) * 384 + h * 48 + dt * 16 + lq] =
          __float2bfloat16(O[dt][r] * inv);
  }
}

// ---------------- proj GEMM (bf16 MFMA): out[b][c][n] = AT[b][n][:] @ proj_w + b ----------------
__global__ __launch_bounds__(256) void k_proj_mfma(
    const __hip_bfloat16* __restrict__ ATb,  // [8][1024][384]
    const __hip_bfloat16* __restrict__ wtp,  // [384][384] (transposed: [cout][cin])
    const float* __restrict__ pb, float* __restrict__ out) {
  __shared__ __align__(16) short As[64 * 72];
  __shared__ __align__(16) short Bs[64 * 72];
  const int c0 = blockIdx.x * 64;
  const int n0 = blockIdx.y * 64;
  const int b = blockIdx.z;
  const int tid = threadIdx.x;
  const int wv = tid >> 6, lane = tid & 63, quad = lane >> 4, lq = lane & 15;
  f32x4 acc[4];
#pragma unroll
  for (int nt = 0; nt < 4; nt++) acc[nt] = (f32x4){0.f, 0.f, 0.f, 0.f};
  for (int kk = 0; kk < CC; kk += 64) {
#pragma unroll
    for (int e = 0; e < 2; e++) {
      int cid = tid + e * 256;
      int row = cid >> 3, g = cid & 7;
      *(short8*)(As + row * 72 + g * 8) =
          *(const short8*)((const short*)wtp + (size_t)(c0 + row) * 384 + kk + g * 8);
      *(short8*)(Bs + row * 72 + g * 8) =
          *(const short8*)((const short*)ATb + ((size_t)(b << 10) + n0 + row) * 384 + kk + g * 8);
    }
    __syncthreads();
    short8 a0 = *(const short8*)(As + (wv * 16 + lq) * 72 + quad * 8);
    short8 a1 = *(const short8*)(As + (wv * 16 + lq) * 72 + 32 + quad * 8);
#pragma unroll
    for (int nt = 0; nt < 4; nt++) {
      acc[nt] = __builtin_amdgcn_mfma_f32_16x16x32_bf16(
          a0, *(const short8*)(Bs + (nt * 16 + lq) * 72 + quad * 8), acc[nt], 0, 0, 0);
      acc[nt] = __builtin_amdgcn_mfma_f32_16x16x32_bf16(
          a1, *(const short8*)(Bs + (nt * 16 + lq) * 72 + 32 + quad * 8), acc[nt], 0, 0, 0);
    }
    __syncthreads();
  }
#pragma unroll
  for (int nt = 0; nt < 4; nt++) {
    int n = n0 + nt * 16 + lq;
#pragma unroll
    for (int r = 0; r < 4; r++) {
      int c = c0 + wv * 16 + quad * 4 + r;
      out[((size_t)b * 384 + c) * 1024 + n] = acc[nt][r] + pb[c];
    }
  }
}

extern "C" void kernel_launch(void* const* d_in, const int* in_sizes, int n_in,
                              void* d_out, int out_size, void* d_ws, size_t ws_size,
                              hipStream_t stream) {
  const float* x = (const float*)d_in[0];
  const float* qkv_w = (const float*)d_in[1];
  const float* qkv_b = (const float*)d_in[2];
  const float* proj_w = (const float*)d_in[3];
  const float* proj_b = (const float*)d_in[4];
  const float* w1 = (const float*)d_in[5];
  const float* b1 = (const float*)d_in[6];
  const float* w2 = (const float*)d_in[7];
  const float* b2 = (const float*)d_in[8];
  float* out = (float*)d_out;

  char* w = (char*)d_ws;
  __hip_bfloat16* xt = (__hip_bfloat16*)w;   w += (size_t)8192 * 384 * 2;
  __hip_bfloat16* wtq = (__hip_bfloat16*)w;  w += (size_t)1152 * 384 * 2;
  __hip_bfloat16* wtp = (__hip_bfloat16*)w;  w += (size_t)384 * 384 * 2;
  __hip_bfloat16* Qb = (__hip_bfloat16*)w;   w += (size_t)64 * 1024 * 64 * 2;
  __hip_bfloat16* Kb = (__hip_bfloat16*)w;   w += (size_t)64 * 1024 * 64 * 2;
  __hip_bfloat16* Vt = (__hip_bfloat16*)w;   w += (size_t)64 * 48 * 1024 * 2;
  __hip_bfloat16* ATb = (__hip_bfloat16*)w;  w += (size_t)8192 * 384 * 2;
  float* tab = (float*)w;                    w += (size_t)8 * 3969 * 4;

  k_bias_table<<<dim3(16), dim3(256), 0, stream>>>(w1, b1, w2, b2, tab);
  k_tcvt<<<dim3(32, 12, 8), dim3(256), 0, stream>>>(x, xt, 384, 1024);
  k_tcvt<<<dim3(36, 12, 1), dim3(256), 0, stream>>>(qkv_w, wtq, 384, 1152);
  k_tcvt<<<dim3(12, 12, 1), dim3(256), 0, stream>>>(proj_w, wtp, 384, 384);
  // zero d-pad region (48..63) of Q/K via full clear
  hipMemsetAsync(Qb, 0, (size_t)64 * 1024 * 64 * 2, stream);
  hipMemsetAsync(Kb, 0, (size_t)64 * 1024 * 64 * 2, stream);
  k_qkv_mfma<<<dim3(128, 18), dim3(256), 0, stream>>>(xt, wtq, qkv_b, Qb, Kb, Vt);
  k_flash<<<dim3(16, 64), dim3(256), 0, stream>>>(Qb, Kb, Vt, tab, ATb);
  k_proj_mfma<<<dim3(6, 16, 8), dim3(256), 0, stream>>>(ATb, wtp, proj_b, out);
}

// Round 3
// 205.999 us; speedup vs baseline: 4.0240x; 1.2439x over previous
//
#include <hip/hip_runtime.h>
#include <hip/hip_bf16.h>
#include <math.h>

#define BB 8
#define CC 384
#define NT 1024
#define NHEAD 8
#define HD 48
#define HIDDEN 192
#define THREEC 1152

typedef short short8 __attribute__((ext_vector_type(8)));
typedef short short4v __attribute__((ext_vector_type(4)));
typedef float f32x4 __attribute__((ext_vector_type(4)));

static __device__ __forceinline__ short bf16bits(float v) {
  __hip_bfloat16 h = __float2bfloat16(v);
  return *(short*)&h;
}

// ---------------- bias table: [8][63*63], pre-scaled by log2(e) ----------------
__global__ __launch_bounds__(256) void k_bias_table(
    const float* __restrict__ w1, const float* __restrict__ b1,
    const float* __restrict__ w2, const float* __restrict__ b2,
    float* __restrict__ tab) {
  int p = blockIdx.x * blockDim.x + threadIdx.x;
  if (p >= 63 * 63) return;
  float rh = (float)(p / 63 - 31) * (1.0f / 31.0f);
  float rw = (float)(p % 63 - 31) * (1.0f / 31.0f);
  float acc[8];
#pragma unroll
  for (int h = 0; h < 8; h++) acc[h] = b2[h];
  for (int j = 0; j < HIDDEN; j++) {
    float pre = fmaf(rh, w1[j], fmaf(rw, w1[HIDDEN + j], b1[j]));
    float g = 0.5f * pre * (1.0f + erff(pre * 0.70710678118654752f));
#pragma unroll
    for (int h = 0; h < 8; h++) acc[h] = fmaf(g, w2[j * 8 + h], acc[h]);
  }
#pragma unroll
  for (int h = 0; h < 8; h++) tab[h * 3969 + p] = acc[h] * 1.4426950408889634f;
}

// ---------------- transpose + fp32->bf16: src[z][R][C] -> dst[z][C][R] ----------------
__global__ __launch_bounds__(256) void k_tcvt(const float* __restrict__ src,
                                              __hip_bfloat16* __restrict__ dst,
                                              int R, int C) {
  __shared__ float t[32][33];
  src += (size_t)blockIdx.z * R * C;
  dst += (size_t)blockIdx.z * R * C;
  const int c0 = blockIdx.x * 32, r0 = blockIdx.y * 32;
  const int tid = threadIdx.x;
#pragma unroll
  for (int e = 0; e < 4; e++) {
    int i = tid + e * 256;
    int r = i >> 5, c = i & 31;
    t[r][c] = src[(size_t)(r0 + r) * C + c0 + c];
  }
  __syncthreads();
#pragma unroll
  for (int e = 0; e < 4; e++) {
    int i = tid + e * 256;
    int c = i >> 5, r = i & 31;
    dst[(size_t)(c0 + c) * R + r0 + r] = __float2bfloat16(t[r][c]);
  }
}

// ---------------- QKV GEMM (bf16 MFMA) ----------------
// Q pre-scaled by 48^-0.5 * log2(e); V written transposed [bh][d][n] via LDS transpose
__global__ __launch_bounds__(256) void k_qkv_mfma(
    const __hip_bfloat16* __restrict__ xt,   // [8192][384]
    const __hip_bfloat16* __restrict__ wtq,  // [1152][384]
    const float* __restrict__ qkv_b,
    __hip_bfloat16* __restrict__ Qb,  // [64][1024][64]
    __hip_bfloat16* __restrict__ Kb,  // [64][1024][64]
    __hip_bfloat16* __restrict__ Vt)  // [64][48][1024]
{
  __shared__ __align__(16) char smem[18432];
  short* As = (short*)smem;            // 64*72 shorts
  short* Bs = (short*)(smem + 9216);   // 64*72 shorts
  float* Vf = (float*)smem;            // 64*68 floats (reuse after loop)
  const int m0 = blockIdx.x * 64;  // token tile
  const int n0 = blockIdx.y * 64;  // out-channel tile
  const int tid = threadIdx.x;
  const int wv = tid >> 6, lane = tid & 63, quad = lane >> 4, lq = lane & 15;
  f32x4 acc[4];
#pragma unroll
  for (int nt = 0; nt < 4; nt++) acc[nt] = (f32x4){0.f, 0.f, 0.f, 0.f};
  for (int kk = 0; kk < CC; kk += 64) {
#pragma unroll
    for (int e = 0; e < 2; e++) {
      int cid = tid + e * 256;
      int row = cid >> 3, g = cid & 7;
      *(short8*)(As + row * 72 + g * 8) =
          *(const short8*)((const short*)xt + (size_t)(m0 + row) * 384 + kk + g * 8);
      *(short8*)(Bs + row * 72 + g * 8) =
          *(const short8*)((const short*)wtq + (size_t)(n0 + row) * 384 + kk + g * 8);
    }
    __syncthreads();
    short8 a0 = *(const short8*)(As + (wv * 16 + lq) * 72 + quad * 8);
    short8 a1 = *(const short8*)(As + (wv * 16 + lq) * 72 + 32 + quad * 8);
#pragma unroll
    for (int nt = 0; nt < 4; nt++) {
      acc[nt] = __builtin_amdgcn_mfma_f32_16x16x32_bf16(
          a0, *(const short8*)(Bs + (nt * 16 + lq) * 72 + quad * 8), acc[nt], 0, 0, 0);
      acc[nt] = __builtin_amdgcn_mfma_f32_16x16x32_bf16(
          a1, *(const short8*)(Bs + (nt * 16 + lq) * 72 + 32 + quad * 8), acc[nt], 0, 0, 0);
    }
    __syncthreads();  // also guarantees LDS reads done before Vf reuse
  }
  const float qscale = 0.14433756729740643f * 1.4426950408889634f;
  if (n0 < 768) {
    // ---- Q or K: direct writes ----
    const int which = n0 >= 384;
#pragma unroll
    for (int nt = 0; nt < 4; nt++) {
      int cg = n0 + nt * 16 + lq;
      float bias = qkv_b[cg];
      int rr = cg - which * 384;
      int head = rr / 48, d = rr - head * 48;
#pragma unroll
      for (int r = 0; r < 4; r++) {
        int token = m0 + wv * 16 + quad * 4 + r;
        int b = token >> 10, n = token & 1023;
        int bh = b * 8 + head;
        float v = acc[nt][r] + bias;
        if (which == 0)
          Qb[((size_t)(bh << 10) + n) * 64 + d] = __float2bfloat16(v * qscale);
        else
          Kb[((size_t)(bh << 10) + n) * 64 + d] = __float2bfloat16(v);
      }
    }
  } else {
    // ---- V: LDS transpose then coalesced store to Vt[bh][d][n] ----
#pragma unroll
    for (int nt = 0; nt < 4; nt++) {
      float bias = qkv_b[n0 + nt * 16 + lq];
#pragma unroll
      for (int r = 0; r < 4; r++)
        Vf[(nt * 16 + lq) * 68 + wv * 16 + quad * 4 + r] = acc[nt][r] + bias;
    }
    __syncthreads();
    int ch = tid & 63, grp = tid >> 6;
    int cg = n0 - 768 + ch;
    int head = cg / 48, d = cg - head * 48;
    int b = m0 >> 10;
    int n = (m0 & 1023) + grp * 16;
    const float* src = Vf + ch * 68 + grp * 16;
    short out16[16];
#pragma unroll
    for (int k = 0; k < 16; k++) out16[k] = bf16bits(src[k]);
    short* dst = (short*)Vt + ((size_t)(b * 8 + head) * 48 + d) * 1024 + n;
    *(short8*)dst = *(short8*)out16;
    *(short8*)(dst + 8) = *(short8*)(out16 + 8);
  }
}

// ---------------- fused flash attention (S^T trick) ----------------
// grid: x = bh (64, XCD-local), y = q-tile (16)
__global__ __launch_bounds__(256, 4) void k_flash(
    const __hip_bfloat16* __restrict__ Qb, const __hip_bfloat16* __restrict__ Kb,
    const __hip_bfloat16* __restrict__ Vt, const float* __restrict__ tab,
    __hip_bfloat16* __restrict__ ATb)  // [8][1024][384]
{
  __shared__ __align__(16) char smem[33792];
  short* Ks_l = (short*)smem;             // 64*72 shorts = 9216 B
  short* Vt_l = (short*)(smem + 9216);    // 48*72 shorts = 6912 B
  short* Ps_l = (short*)(smem + 16128);   // 64*72 shorts = 9216 B
  float* tab_l = (float*)(smem + 25344);  // 33*64 floats = 8448 B
  float* Os = (float*)smem;               // 64*52 floats (reuse, 13312 B)

  const int tid = threadIdx.x;
  const int wv = tid >> 6, lane = tid & 63, quad = lane >> 4, lq = lane & 15;
  const int bh = blockIdx.x;
  const int q0 = blockIdx.y * 64;
  const int b = bh >> 3, h = bh & 7;
  const int inr0 = q0 >> 5;

  // tab slice: only rows [inr0, inr0+32] are reachable from this q-tile
  for (int i = tid; i < 33 * 63; i += 256) {
    int g = i / 63, c = i - g * 63;
    tab_l[g * 64 + c] = tab[h * 3969 + (inr0 + g) * 63 + c];
  }

  const int nrow = q0 + wv * 16 + lq;  // this lane's q-row (S^T: col = q)
  const int jnr = nrow & 31;
  const int rbase = (nrow >> 5) - inr0 + 31;  // tab_l row = rbase - im

  short8 qf0, qf1;
  {
    const short* qp = (const short*)Qb + ((size_t)(bh << 10) + nrow) * 64;
    qf0 = *(const short8*)(qp + quad * 8);
    qf1 = *(const short8*)(qp + 32 + quad * 8);
  }
  f32x4 O[3];
#pragma unroll
  for (int dt = 0; dt < 3; dt++) O[dt] = (f32x4){0.f, 0.f, 0.f, 0.f};
  float M = -1e30f, L = 0.f;

  const short* kgp = (const short*)Kb + ((size_t)(bh << 10)) * 64;
  const short* vgp = (const short*)Vt + (size_t)bh * 48 * 1024;
  const int krow0 = tid >> 3, kg0 = tid & 7;
  const int krow1 = (tid + 256) >> 3, kg1 = tid & 7;
  // prefetch tile 0
  short8 kr0 = *(const short8*)(kgp + (size_t)krow0 * 64 + kg0 * 8);
  short8 kr1 = *(const short8*)(kgp + (size_t)krow1 * 64 + kg1 * 8);
  short8 vr0 = *(const short8*)(vgp + (size_t)krow0 * 1024 + kg0 * 8);
  short8 vr1;
  if (tid < 128) vr1 = *(const short8*)(vgp + (size_t)krow1 * 1024 + kg1 * 8);

  for (int m0 = 0; m0 < NT; m0 += 64) {
    __syncthreads();  // LDS free (prev tile's MFMA reads done)
    *(short8*)(Ks_l + krow0 * 72 + kg0 * 8) = kr0;
    *(short8*)(Ks_l + krow1 * 72 + kg1 * 8) = kr1;
    *(short8*)(Vt_l + krow0 * 72 + kg0 * 8) = vr0;
    if (tid < 128) *(short8*)(Vt_l + krow1 * 72 + kg1 * 8) = vr1;
    if (m0 + 64 < NT) {  // prefetch next tile (overlaps with compute below)
      const short* kt = kgp + (size_t)(m0 + 64) * 64;
      kr0 = *(const short8*)(kt + (size_t)krow0 * 64 + kg0 * 8);
      kr1 = *(const short8*)(kt + (size_t)krow1 * 64 + kg1 * 8);
      vr0 = *(const short8*)(vgp + (size_t)krow0 * 1024 + m0 + 64 + kg0 * 8);
      if (tid < 128) vr1 = *(const short8*)(vgp + (size_t)krow1 * 1024 + m0 + 64 + kg1 * 8);
    }
    __syncthreads();  // LDS ready

    // S^T = mfma(K-frag, Q-frag): lane holds keys {m0+nt*16+quad*4+r} of q-row `nrow`
    float s[4][4];
#pragma unroll
    for (int nt = 0; nt < 4; nt++) {
      f32x4 c = (f32x4){0.f, 0.f, 0.f, 0.f};
      c = __builtin_amdgcn_mfma_f32_16x16x32_bf16(
          *(const short8*)(Ks_l + (nt * 16 + lq) * 72 + quad * 8), qf0, c, 0, 0, 0);
      c = __builtin_amdgcn_mfma_f32_16x16x32_bf16(
          *(const short8*)(Ks_l + (nt * 16 + lq) * 72 + 32 + quad * 8), qf1, c, 0, 0, 0);
#pragma unroll
      for (int r = 0; r < 4; r++) {
        int key = m0 + nt * 16 + quad * 4 + r;
        int im = key >> 5, jm = key & 31;
        s[nt][r] = c[r] + tab_l[(rbase - im) * 64 + (jnr - jm + 31)];
      }
    }
    // online softmax in log2 domain; row lives in 4 lanes (quad butterfly only)
    float tmax = s[0][0];
#pragma unroll
    for (int nt = 0; nt < 4; nt++)
#pragma unroll
      for (int r = 0; r < 4; r++) tmax = fmaxf(tmax, s[nt][r]);
    tmax = fmaxf(tmax, __shfl_xor(tmax, 16));
    tmax = fmaxf(tmax, __shfl_xor(tmax, 32));
    float newM = fmaxf(M, tmax);
    float alpha = exp2f(M - newM);
    M = newM;
    float lsum = 0.f;
#pragma unroll
    for (int nt = 0; nt < 4; nt++)
#pragma unroll
      for (int r = 0; r < 4; r++) {
        s[nt][r] = exp2f(s[nt][r] - newM);
        lsum += s[nt][r];
      }
    L = L * alpha + lsum;  // per-lane partial; reduced across quads at the end
#pragma unroll
    for (int dt = 0; dt < 3; dt++) O[dt] *= alpha;
    // P^T -> LDS rows [q][key] (own-wave round trip: no barrier needed)
#pragma unroll
    for (int nt = 0; nt < 4; nt++) {
      short4v pk;
      pk[0] = bf16bits(s[nt][0]); pk[1] = bf16bits(s[nt][1]);
      pk[2] = bf16bits(s[nt][2]); pk[3] = bf16bits(s[nt][3]);
      *(short4v*)(Ps_l + (wv * 16 + lq) * 72 + nt * 16 + quad * 4) = pk;
    }
    // O^T += mfma(V^T-frag, P^T-frag)
#pragma unroll
    for (int ks = 0; ks < 2; ks++) {
      short8 pf = *(const short8*)(Ps_l + (wv * 16 + lq) * 72 + ks * 32 + quad * 8);
#pragma unroll
      for (int dt = 0; dt < 3; dt++)
        O[dt] = __builtin_amdgcn_mfma_f32_16x16x32_bf16(
            *(const short8*)(Vt_l + (dt * 16 + lq) * 72 + ks * 32 + quad * 8), pf, O[dt], 0, 0, 0);
    }
  }
  L += __shfl_xor(L, 16);
  L += __shfl_xor(L, 32);
  float inv = 1.0f / L;
  __syncthreads();  // all PV reads done before Os aliases Ks/Vt
#pragma unroll
  for (int dt = 0; dt < 3; dt++)
#pragma unroll
    for (int r = 0; r < 4; r++)
      Os[(wv * 16 + lq) * 52 + dt * 16 + quad * 4 + r] = O[dt][r] * inv;
  __syncthreads();
  {
    int row = tid >> 2, cg = (tid & 3) * 12;
    const float* src = Os + row * 52 + cg;
    short outp[12];
#pragma unroll
    for (int k = 0; k < 12; k++) outp[k] = bf16bits(src[k]);
    short* dst = (short*)ATb + ((size_t)(b << 10) + q0 + row) * 384 + h * 48 + cg;
    *(short4v*)dst = *(short4v*)outp;
    *(short4v*)(dst + 4) = *(short4v*)(outp + 4);
    *(short4v*)(dst + 8) = *(short4v*)(outp + 8);
  }
}

// ---------------- proj GEMM (bf16 MFMA) ----------------
__global__ __launch_bounds__(256) void k_proj_mfma(
    const __hip_bfloat16* __restrict__ ATb,  // [8][1024][384]
    const __hip_bfloat16* __restrict__ wtp,  // [384][384] ([cout][cin])
    const float* __restrict__ pb, float* __restrict__ out) {
  __shared__ __align__(16) short As[64 * 72];
  __shared__ __align__(16) short Bs[64 * 72];
  const int c0 = blockIdx.x * 64;
  const int n0 = blockIdx.y * 64;
  const int b = blockIdx.z;
  const int tid = threadIdx.x;
  const int wv = tid >> 6, lane = tid & 63, quad = lane >> 4, lq = lane & 15;
  f32x4 acc[4];
#pragma unroll
  for (int nt = 0; nt < 4; nt++) acc[nt] = (f32x4){0.f, 0.f, 0.f, 0.f};
  for (int kk = 0; kk < CC; kk += 64) {
#pragma unroll
    for (int e = 0; e < 2; e++) {
      int cid = tid + e * 256;
      int row = cid >> 3, g = cid & 7;
      *(short8*)(As + row * 72 + g * 8) =
          *(const short8*)((const short*)wtp + (size_t)(c0 + row) * 384 + kk + g * 8);
      *(short8*)(Bs + row * 72 + g * 8) =
          *(const short8*)((const short*)ATb + ((size_t)(b << 10) + n0 + row) * 384 + kk + g * 8);
    }
    __syncthreads();
    short8 a0 = *(const short8*)(As + (wv * 16 + lq) * 72 + quad * 8);
    short8 a1 = *(const short8*)(As + (wv * 16 + lq) * 72 + 32 + quad * 8);
#pragma unroll
    for (int nt = 0; nt < 4; nt++) {
      acc[nt] = __builtin_amdgcn_mfma_f32_16x16x32_bf16(
          a0, *(const short8*)(Bs + (nt * 16 + lq) * 72 + quad * 8), acc[nt], 0, 0, 0);
      acc[nt] = __builtin_amdgcn_mfma_f32_16x16x32_bf16(
          a1, *(const short8*)(Bs + (nt * 16 + lq) * 72 + 32 + quad * 8), acc[nt], 0, 0, 0);
    }
    __syncthreads();
  }
#pragma unroll
  for (int nt = 0; nt < 4; nt++) {
    int n = n0 + nt * 16 + lq;
#pragma unroll
    for (int r = 0; r < 4; r++) {
      int c = c0 + wv * 16 + quad * 4 + r;
      out[((size_t)b * 384 + c) * 1024 + n] = acc[nt][r] + pb[c];
    }
  }
}

extern "C" void kernel_launch(void* const* d_in, const int* in_sizes, int n_in,
                              void* d_out, int out_size, void* d_ws, size_t ws_size,
                              hipStream_t stream) {
  const float* x = (const float*)d_in[0];
  const float* qkv_w = (const float*)d_in[1];
  const float* qkv_b = (const float*)d_in[2];
  const float* proj_w = (const float*)d_in[3];
  const float* proj_b = (const float*)d_in[4];
  const float* w1 = (const float*)d_in[5];
  const float* b1 = (const float*)d_in[6];
  const float* w2 = (const float*)d_in[7];
  const float* b2 = (const float*)d_in[8];
  float* out = (float*)d_out;

  char* w = (char*)d_ws;
  __hip_bfloat16* xt = (__hip_bfloat16*)w;   w += (size_t)8192 * 384 * 2;
  __hip_bfloat16* wtq = (__hip_bfloat16*)w;  w += (size_t)1152 * 384 * 2;
  __hip_bfloat16* wtp = (__hip_bfloat16*)w;  w += (size_t)384 * 384 * 2;
  __hip_bfloat16* Qb = (__hip_bfloat16*)w;   w += (size_t)64 * 1024 * 64 * 2;
  __hip_bfloat16* Kb = (__hip_bfloat16*)w;   w += (size_t)64 * 1024 * 64 * 2;
  __hip_bfloat16* Vt = (__hip_bfloat16*)w;   w += (size_t)64 * 48 * 1024 * 2;
  __hip_bfloat16* ATb = (__hip_bfloat16*)w;  w += (size_t)8192 * 384 * 2;
  float* tab = (float*)w;                    w += (size_t)8 * 3969 * 4;

  k_bias_table<<<dim3(16), dim3(256), 0, stream>>>(w1, b1, w2, b2, tab);
  k_tcvt<<<dim3(32, 12, 8), dim3(256), 0, stream>>>(x, xt, 384, 1024);
  k_tcvt<<<dim3(36, 12, 1), dim3(256), 0, stream>>>(qkv_w, wtq, 384, 1152);
  k_tcvt<<<dim3(12, 12, 1), dim3(256), 0, stream>>>(proj_w, wtp, 384, 384);
  hipMemsetAsync(Qb, 0, (size_t)64 * 1024 * 64 * 2, stream);
  hipMemsetAsync(Kb, 0, (size_t)64 * 1024 * 64 * 2, stream);
  k_qkv_mfma<<<dim3(128, 18), dim3(256), 0, stream>>>(xt, wtq, qkv_b, Qb, Kb, Vt);
  k_flash<<<dim3(64, 16), dim3(256), 0, stream>>>(Qb, Kb, Vt, tab, ATb);
  k_proj_mfma<<<dim3(6, 16, 8), dim3(256), 0, stream>>>(ATb, wtp, proj_b, out);
}

// Round 4
// 172.909 us; speedup vs baseline: 4.7941x; 1.1914x over previous
//
#include <hip/hip_runtime.h>
#include <hip/hip_bf16.h>
#include <math.h>

#define BB 8
#define CC 384
#define NT 1024
#define NHEAD 8
#define HD 48
#define HIDDEN 192
#define THREEC 1152

typedef short short8 __attribute__((ext_vector_type(8)));
typedef short short4v __attribute__((ext_vector_type(4)));
typedef float f32x4 __attribute__((ext_vector_type(4)));
typedef unsigned int uint2v __attribute__((ext_vector_type(2)));

static __device__ __forceinline__ short bf16bits(float v) {
  __hip_bfloat16 h = __float2bfloat16(v);
  return *(short*)&h;
}
// pack two fp32 -> two bf16 (round-half-up) in 3 ops via v_perm_b32
static __device__ __forceinline__ unsigned pk2(float a, float b) {
  return __builtin_amdgcn_perm(__float_as_uint(b) + 0x8000u,
                               __float_as_uint(a) + 0x8000u, 0x07060302u);
}

// ---------------- bias table: [8][63*63], pre-scaled by log2(e) ----------------
// 8 threads per entry (24 hidden units each), butterfly-reduced in-wave
__global__ __launch_bounds__(256) void k_bias_table(
    const float* __restrict__ w1, const float* __restrict__ b1,
    const float* __restrict__ w2, const float* __restrict__ b2,
    float* __restrict__ tab) {
  int g = blockIdx.x * 256 + threadIdx.x;
  int p = g >> 3, jc = g & 7;
  if (p >= 63 * 63) return;
  float rh = (float)(p / 63 - 31) * (1.0f / 31.0f);
  float rw = (float)(p % 63 - 31) * (1.0f / 31.0f);
  float acc[8] = {0.f, 0.f, 0.f, 0.f, 0.f, 0.f, 0.f, 0.f};
  const int j0 = jc * 24;
#pragma unroll 4
  for (int j = j0; j < j0 + 24; j++) {
    float pre = fmaf(rh, w1[j], fmaf(rw, w1[HIDDEN + j], b1[j]));
    float gl = 0.5f * pre * (1.0f + erff(pre * 0.70710678118654752f));
#pragma unroll
    for (int h = 0; h < 8; h++) acc[h] = fmaf(gl, w2[j * 8 + h], acc[h]);
  }
#pragma unroll
  for (int msk = 1; msk <= 4; msk <<= 1)
#pragma unroll
    for (int h = 0; h < 8; h++) acc[h] += __shfl_xor(acc[h], msk);
  if (jc == 0) {
#pragma unroll
    for (int h = 0; h < 8; h++)
      tab[h * 3969 + p] = (acc[h] + b2[h]) * 1.4426950408889634f;
  }
}

// ---------------- transpose + fp32->bf16: src[z][R][C] -> dst[z][C][R] ----------------
__global__ __launch_bounds__(256) void k_tcvt(const float* __restrict__ src,
                                              __hip_bfloat16* __restrict__ dst,
                                              int R, int C) {
  __shared__ float t[32][33];
  src += (size_t)blockIdx.z * R * C;
  dst += (size_t)blockIdx.z * R * C;
  const int c0 = blockIdx.x * 32, r0 = blockIdx.y * 32;
  const int tid = threadIdx.x;
#pragma unroll
  for (int e = 0; e < 4; e++) {
    int i = tid + e * 256;
    int r = i >> 5, c = i & 31;
    t[r][c] = src[(size_t)(r0 + r) * C + c0 + c];
  }
  __syncthreads();
#pragma unroll
  for (int e = 0; e < 4; e++) {
    int i = tid + e * 256;
    int c = i >> 5, r = i & 31;
    dst[(size_t)(c0 + c) * R + r0 + r] = __float2bfloat16(t[r][c]);
  }
}

// ---------------- QKV GEMM (bf16 MFMA) ----------------
__global__ __launch_bounds__(256) void k_qkv_mfma(
    const __hip_bfloat16* __restrict__ xt,   // [8192][384]
    const __hip_bfloat16* __restrict__ wtq,  // [1152][384]
    const float* __restrict__ qkv_b,
    __hip_bfloat16* __restrict__ Qb,  // [64][1024][64]
    __hip_bfloat16* __restrict__ Kb,  // [64][1024][64]
    __hip_bfloat16* __restrict__ Vt)  // [64][48][1024]
{
  __shared__ __align__(16) char smem[18432];
  short* As = (short*)smem;
  short* Bs = (short*)(smem + 9216);
  float* Vf = (float*)smem;  // reuse
  const int m0 = blockIdx.x * 64;
  const int n0 = blockIdx.y * 64;
  const int tid = threadIdx.x;
  const int wv = tid >> 6, lane = tid & 63, quad = lane >> 4, lq = lane & 15;
  f32x4 acc[4];
#pragma unroll
  for (int nt = 0; nt < 4; nt++) acc[nt] = (f32x4){0.f, 0.f, 0.f, 0.f};
  for (int kk = 0; kk < CC; kk += 64) {
#pragma unroll
    for (int e = 0; e < 2; e++) {
      int cid = tid + e * 256;
      int row = cid >> 3, g = cid & 7;
      *(short8*)(As + row * 72 + g * 8) =
          *(const short8*)((const short*)xt + (size_t)(m0 + row) * 384 + kk + g * 8);
      *(short8*)(Bs + row * 72 + g * 8) =
          *(const short8*)((const short*)wtq + (size_t)(n0 + row) * 384 + kk + g * 8);
    }
    __syncthreads();
    short8 a0 = *(const short8*)(As + (wv * 16 + lq) * 72 + quad * 8);
    short8 a1 = *(const short8*)(As + (wv * 16 + lq) * 72 + 32 + quad * 8);
#pragma unroll
    for (int nt = 0; nt < 4; nt++) {
      acc[nt] = __builtin_amdgcn_mfma_f32_16x16x32_bf16(
          a0, *(const short8*)(Bs + (nt * 16 + lq) * 72 + quad * 8), acc[nt], 0, 0, 0);
      acc[nt] = __builtin_amdgcn_mfma_f32_16x16x32_bf16(
          a1, *(const short8*)(Bs + (nt * 16 + lq) * 72 + 32 + quad * 8), acc[nt], 0, 0, 0);
    }
    __syncthreads();
  }
  const float qscale = 0.14433756729740643f * 1.4426950408889634f;
  if (n0 < 768) {
    const int which = n0 >= 384;
#pragma unroll
    for (int nt = 0; nt < 4; nt++) {
      int cg = n0 + nt * 16 + lq;
      float bias = qkv_b[cg];
      int rr = cg - which * 384;
      int head = rr / 48, d = rr - head * 48;
#pragma unroll
      for (int r = 0; r < 4; r++) {
        int token = m0 + wv * 16 + quad * 4 + r;
        int b = token >> 10, n = token & 1023;
        int bh = b * 8 + head;
        float v = acc[nt][r] + bias;
        if (which == 0)
          Qb[((size_t)(bh << 10) + n) * 64 + d] = __float2bfloat16(v * qscale);
        else
          Kb[((size_t)(bh << 10) + n) * 64 + d] = __float2bfloat16(v);
      }
    }
  } else {
#pragma unroll
    for (int nt = 0; nt < 4; nt++) {
      float bias = qkv_b[n0 + nt * 16 + lq];
#pragma unroll
      for (int r = 0; r < 4; r++)
        Vf[(nt * 16 + lq) * 68 + wv * 16 + quad * 4 + r] = acc[nt][r] + bias;
    }
    __syncthreads();
    int ch = tid & 63, grp = tid >> 6;
    int cg = n0 - 768 + ch;
    int head = cg / 48, d = cg - head * 48;
    int b = m0 >> 10;
    int n = (m0 & 1023) + grp * 16;
    const float* src = Vf + ch * 68 + grp * 16;
    short out16[16];
#pragma unroll
    for (int k = 0; k < 16; k++) out16[k] = bf16bits(src[k]);
    short* dst = (short*)Vt + ((size_t)(b * 8 + head) * 48 + d) * 1024 + n;
    *(short8*)dst = *(short8*)out16;
    *(short8*)(dst + 8) = *(short8*)(out16 + 8);
  }
}

// ---------------- fused flash attention (S^T trick, ping-pong prefetch) ----------------
__global__ __launch_bounds__(256, 4) void k_flash(
    const __hip_bfloat16* __restrict__ Qb, const __hip_bfloat16* __restrict__ Kb,
    const __hip_bfloat16* __restrict__ Vt, const float* __restrict__ tab,
    __hip_bfloat16* __restrict__ ATb)  // [8][1024][384]
{
  __shared__ __align__(16) char smem[33792];
  short* Ks_l = (short*)smem;             // 64*72 shorts
  short* Vt_l = (short*)(smem + 9216);    // 48*72 shorts
  short* Ps_l = (short*)(smem + 16128);   // 64*72 shorts
  float* tab_l = (float*)(smem + 25344);  // 33*64 floats
  float* Os = (float*)smem;               // reuse

  const int tid = threadIdx.x;
  const int wv = tid >> 6, lane = tid & 63, quad = lane >> 4, lq = lane & 15;
  const int bh = blockIdx.x;
  const int q0 = blockIdx.y * 64;
  const int b = bh >> 3, h = bh & 7;
  const int inr0 = q0 >> 5;

  for (int i = tid; i < 33 * 63; i += 256) {
    int g = i / 63, c = i - g * 63;
    tab_l[g * 64 + c] = tab[h * 3969 + (inr0 + g) * 63 + c];
  }

  const int nrow = q0 + wv * 16 + lq;
  const int jnr = nrow & 31;
  const int rbase = (nrow >> 5) - inr0 + 31;
  // hoisted tab base (dwords): idx(nt,r,m0) = vb - (m0>>5)*64 - (nt>>1)*64 - (nt&1)*16 - r
  const int vb = rbase * 64 + jnr + 31 - quad * 4;

  short8 qf0, qf1;
  {
    const short* qp = (const short*)Qb + ((size_t)(bh << 10) + nrow) * 64;
    qf0 = *(const short8*)(qp + quad * 8);
    qf1 = *(const short8*)(qp + 32 + quad * 8);
  }
  f32x4 O[3];
#pragma unroll
  for (int dt = 0; dt < 3; dt++) O[dt] = (f32x4){0.f, 0.f, 0.f, 0.f};
  float M = -1e30f, L = 0.f;

  const short* kgp = (const short*)Kb + ((size_t)(bh << 10)) * 64;
  const short* vgp = (const short*)Vt + (size_t)bh * 48 * 1024;
  const int krow0 = tid >> 3, kg0 = tid & 7;
  const int krow1 = (tid + 256) >> 3;

  short8 kA0, kA1, vA0, vA1, kB0, kB1, vB0, vB1;

  auto fetch = [&](int m0, short8& k0, short8& k1, short8& v0, short8& v1) {
    const short* kt = kgp + (size_t)m0 * 64;
    k0 = *(const short8*)(kt + (size_t)krow0 * 64 + kg0 * 8);
    k1 = *(const short8*)(kt + (size_t)krow1 * 64 + kg0 * 8);
    v0 = *(const short8*)(vgp + (size_t)krow0 * 1024 + m0 + kg0 * 8);
    if (tid < 128) v1 = *(const short8*)(vgp + (size_t)krow1 * 1024 + m0 + kg0 * 8);
  };
  auto stage = [&](short8 k0, short8 k1, short8 v0, short8 v1) {
    *(short8*)(Ks_l + krow0 * 72 + kg0 * 8) = k0;
    *(short8*)(Ks_l + krow1 * 72 + kg0 * 8) = k1;
    *(short8*)(Vt_l + krow0 * 72 + kg0 * 8) = v0;
    if (tid < 128) *(short8*)(Vt_l + krow1 * 72 + kg0 * 8) = v1;
  };
  auto compute = [&](int m0) {
    float s[4][4];
    const float* tb = tab_l + vb - (m0 >> 5) * 64;
#pragma unroll
    for (int nt = 0; nt < 4; nt++) {
      f32x4 c = (f32x4){0.f, 0.f, 0.f, 0.f};
      c = __builtin_amdgcn_mfma_f32_16x16x32_bf16(
          *(const short8*)(Ks_l + (nt * 16 + lq) * 72 + quad * 8), qf0, c, 0, 0, 0);
      c = __builtin_amdgcn_mfma_f32_16x16x32_bf16(
          *(const short8*)(Ks_l + (nt * 16 + lq) * 72 + 32 + quad * 8), qf1, c, 0, 0, 0);
#pragma unroll
      for (int r = 0; r < 4; r++)
        s[nt][r] = c[r] + tb[-((nt >> 1) * 64 + (nt & 1) * 16 + r)];
    }
    float tmax = s[0][0];
#pragma unroll
    for (int nt = 0; nt < 4; nt++)
#pragma unroll
      for (int r = 0; r < 4; r++) tmax = fmaxf(tmax, s[nt][r]);
    // 4-lane all-gather max: 3 independent shuffles, one latency round
    float m16 = __shfl_xor(tmax, 16), m32 = __shfl_xor(tmax, 32), m48 = __shfl_xor(tmax, 48);
    tmax = fmaxf(fmaxf(tmax, m16), fmaxf(m32, m48));
    float newM = fmaxf(M, tmax);
    float alpha = exp2f(M - newM);
    M = newM;
    float lsum = 0.f;
#pragma unroll
    for (int nt = 0; nt < 4; nt++)
#pragma unroll
      for (int r = 0; r < 4; r++) {
        s[nt][r] = exp2f(s[nt][r] - newM);
        lsum += s[nt][r];
      }
    L = L * alpha + lsum;
#pragma unroll
    for (int dt = 0; dt < 3; dt++) O[dt] *= alpha;
#pragma unroll
    for (int nt = 0; nt < 4; nt++) {
      uint2v pw;
      pw[0] = pk2(s[nt][0], s[nt][1]);
      pw[1] = pk2(s[nt][2], s[nt][3]);
      *(uint2v*)(Ps_l + (wv * 16 + lq) * 72 + nt * 16 + quad * 4) = pw;
    }
#pragma unroll
    for (int ks = 0; ks < 2; ks++) {
      short8 pf = *(const short8*)(Ps_l + (wv * 16 + lq) * 72 + ks * 32 + quad * 8);
#pragma unroll
      for (int dt = 0; dt < 3; dt++)
        O[dt] = __builtin_amdgcn_mfma_f32_16x16x32_bf16(
            *(const short8*)(Vt_l + (dt * 16 + lq) * 72 + ks * 32 + quad * 8), pf, O[dt], 0, 0, 0);
    }
  };

  fetch(0, kA0, kA1, vA0, vA1);
  for (int t = 0; t < NT; t += 128) {
    __syncthreads();
    stage(kA0, kA1, vA0, vA1);
    __syncthreads();
    if (t + 64 < NT) fetch(t + 64, kB0, kB1, vB0, vB1);
    compute(t);
    __syncthreads();
    stage(kB0, kB1, vB0, vB1);
    __syncthreads();
    if (t + 128 < NT) fetch(t + 128, kA0, kA1, vA0, vA1);
    compute(t + 64);
  }
  // final L all-gather (3 independent shuffles)
  {
    float l16 = __shfl_xor(L, 16), l32 = __shfl_xor(L, 32), l48 = __shfl_xor(L, 48);
    L = (L + l16) + (l32 + l48);
  }
  float inv = 1.0f / L;
  __syncthreads();
#pragma unroll
  for (int dt = 0; dt < 3; dt++)
#pragma unroll
    for (int r = 0; r < 4; r++)
      Os[(wv * 16 + lq) * 52 + dt * 16 + quad * 4 + r] = O[dt][r] * inv;
  __syncthreads();
  {
    int row = tid >> 2, cg = (tid & 3) * 12;
    const float* src = Os + row * 52 + cg;
    short outp[12];
#pragma unroll
    for (int k = 0; k < 12; k++) outp[k] = bf16bits(src[k]);
    short* dst = (short*)ATb + ((size_t)(b << 10) + q0 + row) * 384 + h * 48 + cg;
    *(short4v*)dst = *(short4v*)outp;
    *(short4v*)(dst + 4) = *(short4v*)(outp + 4);
    *(short4v*)(dst + 8) = *(short4v*)(outp + 8);
  }
}

// ---------------- proj GEMM (bf16 MFMA) ----------------
__global__ __launch_bounds__(256) void k_proj_mfma(
    const __hip_bfloat16* __restrict__ ATb,  // [8][1024][384]
    const __hip_bfloat16* __restrict__ wtp,  // [384][384] ([cout][cin])
    const float* __restrict__ pb, float* __restrict__ out) {
  __shared__ __align__(16) short As[64 * 72];
  __shared__ __align__(16) short Bs[64 * 72];
  const int c0 = blockIdx.x * 64;
  const int n0 = blockIdx.y * 64;
  const int b = blockIdx.z;
  const int tid = threadIdx.x;
  const int wv = tid >> 6, lane = tid & 63, quad = lane >> 4, lq = lane & 15;
  f32x4 acc[4];
#pragma unroll
  for (int nt = 0; nt < 4; nt++) acc[nt] = (f32x4){0.f, 0.f, 0.f, 0.f};
  for (int kk = 0; kk < CC; kk += 64) {
#pragma unroll
    for (int e = 0; e < 2; e++) {
      int cid = tid + e * 256;
      int row = cid >> 3, g = cid & 7;
      *(short8*)(As + row * 72 + g * 8) =
          *(const short8*)((const short*)wtp + (size_t)(c0 + row) * 384 + kk + g * 8);
      *(short8*)(Bs + row * 72 + g * 8) =
          *(const short8*)((const short*)ATb + ((size_t)(b << 10) + n0 + row) * 384 + kk + g * 8);
    }
    __syncthreads();
    short8 a0 = *(const short8*)(As + (wv * 16 + lq) * 72 + quad * 8);
    short8 a1 = *(const short8*)(As + (wv * 16 + lq) * 72 + 32 + quad * 8);
#pragma unroll
    for (int nt = 0; nt < 4; nt++) {
      acc[nt] = __builtin_amdgcn_mfma_f32_16x16x32_bf16(
          a0, *(const short8*)(Bs + (nt * 16 + lq) * 72 + quad * 8), acc[nt], 0, 0, 0);
      acc[nt] = __builtin_amdgcn_mfma_f32_16x16x32_bf16(
          a1, *(const short8*)(Bs + (nt * 16 + lq) * 72 + 32 + quad * 8), acc[nt], 0, 0, 0);
    }
    __syncthreads();
  }
#pragma unroll
  for (int nt = 0; nt < 4; nt++) {
    int n = n0 + nt * 16 + lq;
#pragma unroll
    for (int r = 0; r < 4; r++) {
      int c = c0 + wv * 16 + quad * 4 + r;
      out[((size_t)b * 384 + c) * 1024 + n] = acc[nt][r] + pb[c];
    }
  }
}

extern "C" void kernel_launch(void* const* d_in, const int* in_sizes, int n_in,
                              void* d_out, int out_size, void* d_ws, size_t ws_size,
                              hipStream_t stream) {
  const float* x = (const float*)d_in[0];
  const float* qkv_w = (const float*)d_in[1];
  const float* qkv_b = (const float*)d_in[2];
  const float* proj_w = (const float*)d_in[3];
  const float* proj_b = (const float*)d_in[4];
  const float* w1 = (const float*)d_in[5];
  const float* b1 = (const float*)d_in[6];
  const float* w2 = (const float*)d_in[7];
  const float* b2 = (const float*)d_in[8];
  float* out = (float*)d_out;

  char* w = (char*)d_ws;
  __hip_bfloat16* xt = (__hip_bfloat16*)w;   w += (size_t)8192 * 384 * 2;
  __hip_bfloat16* wtq = (__hip_bfloat16*)w;  w += (size_t)1152 * 384 * 2;
  __hip_bfloat16* wtp = (__hip_bfloat16*)w;  w += (size_t)384 * 384 * 2;
  __hip_bfloat16* Qb = (__hip_bfloat16*)w;   w += (size_t)64 * 1024 * 64 * 2;
  __hip_bfloat16* Kb = (__hip_bfloat16*)w;   w += (size_t)64 * 1024 * 64 * 2;
  __hip_bfloat16* Vt = (__hip_bfloat16*)w;   w += (size_t)64 * 48 * 1024 * 2;
  __hip_bfloat16* ATb = (__hip_bfloat16*)w;  w += (size_t)8192 * 384 * 2;
  float* tab = (float*)w;                    w += (size_t)8 * 3969 * 4;

  k_bias_table<<<dim3(125), dim3(256), 0, stream>>>(w1, b1, w2, b2, tab);
  k_tcvt<<<dim3(32, 12, 8), dim3(256), 0, stream>>>(x, xt, 384, 1024);
  k_tcvt<<<dim3(36, 12, 1), dim3(256), 0, stream>>>(qkv_w, wtq, 384, 1152);
  k_tcvt<<<dim3(12, 12, 1), dim3(256), 0, stream>>>(proj_w, wtp, 384, 384);
  hipMemsetAsync(Qb, 0, (size_t)64 * 1024 * 64 * 2, stream);
  hipMemsetAsync(Kb, 0, (size_t)64 * 1024 * 64 * 2, stream);
  k_qkv_mfma<<<dim3(128, 18), dim3(256), 0, stream>>>(xt, wtq, qkv_b, Qb, Kb, Vt);
  k_flash<<<dim3(64, 16), dim3(256), 0, stream>>>(Qb, Kb, Vt, tab, ATb);
  k_proj_mfma<<<dim3(6, 16, 8), dim3(256), 0, stream>>>(ATb, wtp, proj_b, out);
}